// Round 8
// baseline (633.087 us; speedup 1.0000x reference)
//
#include <hip/hip_runtime.h>

#define N_NODES 50000
#define N_EDGES 800000
#define IN_CH 128
#define HID_CH 96
#define OUT_CH 40
#define EPS 1e-5f

// ---------------- bf16 pack/unpack ----------------

__device__ __forceinline__ unsigned packbf(float a, float b) {
    unsigned ua = __float_as_uint(a), ub = __float_as_uint(b);
    ua += 0x7fffu + ((ua >> 16) & 1u);           // RTNE
    ub += 0x7fffu + ((ub >> 16) & 1u);
    return (ua >> 16) | (ub & 0xffff0000u);
}

__device__ __forceinline__ void up4(uint2 u, float* f) {
    f[0] = __uint_as_float(u.x << 16);
    f[1] = __uint_as_float(u.x & 0xffff0000u);
    f[2] = __uint_as_float(u.y << 16);
    f[3] = __uint_as_float(u.y & 0xffff0000u);
}

struct f8 { float4 lo, hi; };

__device__ __forceinline__ f8 unpack8(uint4 v) {
    f8 r;
    r.lo = make_float4(__uint_as_float(v.x << 16), __uint_as_float(v.x & 0xffff0000u),
                       __uint_as_float(v.y << 16), __uint_as_float(v.y & 0xffff0000u));
    r.hi = make_float4(__uint_as_float(v.z << 16), __uint_as_float(v.z & 0xffff0000u),
                       __uint_as_float(v.w << 16), __uint_as_float(v.w & 0xffff0000u));
    return r;
}

// ---------------- CSR build ----------------

__global__ void count_kernel(const int* __restrict__ ei, int* __restrict__ cnt) {
    int e = blockIdx.x * blockDim.x + threadIdx.x;
    if (e >= N_EDGES) return;
    int s = ei[e], d = ei[N_EDGES + e];
    if (s != d) atomicAdd(&cnt[d], 1);
}

__global__ void norm_kernel(const int* __restrict__ cnt, float* __restrict__ dinv,
                            float* __restrict__ selfw) {
    int n = blockIdx.x * blockDim.x + threadIdx.x;
    if (n >= N_NODES) return;
    float deg = (float)(cnt[n] + 1);
    dinv[n]  = rsqrtf(deg);
    selfw[n] = 1.0f / deg;
}

__global__ void scan_kernel(const int* __restrict__ cnt, int* __restrict__ row_start) {
    __shared__ int partial[256];
    const int T = 256;
    int tid = threadIdx.x;
    int seg = (N_NODES + T - 1) / T;
    int s0 = tid * seg;
    int s1 = s0 + seg; if (s1 > N_NODES) s1 = N_NODES;
    int sum = 0;
    for (int i = s0; i < s1; i++) sum += cnt[i];
    partial[tid] = sum;
    __syncthreads();
    if (tid == 0) {
        int acc = 0;
        for (int i = 0; i < T; i++) { int v = partial[i]; partial[i] = acc; acc += v; }
    }
    __syncthreads();
    int acc = partial[tid];
    for (int i = s0; i < s1; i++) { row_start[i] = acc; acc += cnt[i]; }
    if (tid == T - 1) row_start[N_NODES] = acc;
}

__global__ void fill_kernel(const int* __restrict__ ei, const int* __restrict__ row_start,
                            int* __restrict__ fillp, const float* __restrict__ dinv,
                            int2* __restrict__ cw) {
    int e = blockIdx.x * blockDim.x + threadIdx.x;
    if (e >= N_EDGES) return;
    int s = ei[e], d = ei[N_EDGES + e];
    if (s == d) return;
    int p = atomicAdd(&fillp[d], 1);
    int idx = row_start[d] + p;
    cw[idx] = make_int2(s, __float_as_int(dinv[s] * dinv[d]));
}

__global__ void bn_fin(const float* __restrict__ sums, const float* __restrict__ sq,
                       float* __restrict__ mu, float* __restrict__ inv) {
    int c = threadIdx.x;
    if (c >= HID_CH) return;
    float m = sums[c] * (1.0f / N_NODES);
    float v = sq[c] * (1.0f / N_NODES) - m * m;
    mu[c] = m; inv[c] = rsqrtf(v + EPS);
}

// ---------------- GEMM v6: bf16 LDS tiles (X and W), fp32 accumulate ----------
// 256 thr: ob = tid & (NCT-1) channel-lane (channels ob+NCT*j); rl = tid/NCT row-lane
// (rows rl + RT*t). LDS halved vs fp32 -> 3-4 blocks/CU (r7 was latency-bound at 2).
// XBF16: input is packed-bf16 u32 pairs. NORMX: BN+ReLU at stage. BLEND: GCNII blend
// from sX. Output always packed bf16 (pairs via __shfl_xor 1). H0OUT: raw LDS u32 copy.

template <int K, int C, int NCT, int CJ, int NT,
          bool XBF16, bool BLEND, bool NORMX, bool STATS, bool H0OUT>
__global__ __launch_bounds__(256, 4) void gemm6(
    const void* __restrict__ Xv, const float* __restrict__ W,
    unsigned* __restrict__ outb, unsigned* __restrict__ h0n,
    const float* __restrict__ muin, const float* __restrict__ invin,
    float* __restrict__ osum, float* __restrict__ osq, float beta) {
    constexpr int K4 = K / 4;
    constexpr int KP2 = (K == 128) ? 68 : 52;   // u32 row stride (bank-spread, 8B-aligned)
    constexpr int RT = 256 / NCT;
    constexpr int RPB = RT * NT;                // 64
    __shared__ unsigned sW[C * KP2];
    __shared__ unsigned sX[RPB * KP2];
    const int tid = threadIdx.x;
    const int ob = tid & (NCT - 1);
    const int rl = tid / NCT;
    const int nbase = (int)blockIdx.x * RPB;
    const float4* W4 = (const float4*)W;

    // stage W (fp32 global -> bf16 LDS)
    for (int i = tid; i < C * K4; i += 256) {
        int o = i / K4, k4 = i - o * K4;
        float4 wv = W4[(size_t)o * K4 + k4];
        uint2 pk; pk.x = packbf(wv.x, wv.y); pk.y = packbf(wv.z, wv.w);
        *(uint2*)&sW[o * KP2 + k4 * 2] = pk;
    }
    // stage X
    for (int i = tid; i < RPB * K4; i += 256) {
        int r = i / K4, k4 = i - r * K4;
        int n = nbase + r;
        float f[4] = {0.f, 0.f, 0.f, 0.f};
        if (n < N_NODES) {
            if (XBF16) {
                uint2 u = *(const uint2*)&((const unsigned*)Xv)[(size_t)n * (K / 2) + k4 * 2];
                up4(u, f);
            } else {
                float4 v = ((const float4*)Xv)[(size_t)n * K4 + k4];
                f[0] = v.x; f[1] = v.y; f[2] = v.z; f[3] = v.w;
            }
        }
        if (NORMX) {
            float4 m  = *(const float4*)&muin[k4 * 4];
            float4 iv = *(const float4*)&invin[k4 * 4];
            f[0] = fmaxf((f[0] - m.x) * iv.x, 0.0f);
            f[1] = fmaxf((f[1] - m.y) * iv.y, 0.0f);
            f[2] = fmaxf((f[2] - m.z) * iv.z, 0.0f);
            f[3] = fmaxf((f[3] - m.w) * iv.w, 0.0f);
        }
        uint2 pk; pk.x = packbf(f[0], f[1]); pk.y = packbf(f[2], f[3]);
        *(uint2*)&sX[r * KP2 + k4 * 2] = pk;
    }
    __syncthreads();

    float acc[NT][CJ];
#pragma unroll
    for (int t = 0; t < NT; t++)
#pragma unroll
        for (int j = 0; j < CJ; j++) acc[t][j] = 0.0f;

#pragma unroll 2
    for (int k4 = 0; k4 < K4; ++k4) {
        float xv[NT][4], wv[CJ][4];
#pragma unroll
        for (int t = 0; t < NT; ++t)
            up4(*(const uint2*)&sX[(rl + RT * t) * KP2 + k4 * 2], xv[t]);
#pragma unroll
        for (int j = 0; j < CJ; ++j)
            up4(*(const uint2*)&sW[(ob + NCT * j) * KP2 + k4 * 2], wv[j]);
#pragma unroll
        for (int t = 0; t < NT; ++t)
#pragma unroll
            for (int j = 0; j < CJ; ++j) {
                acc[t][j] = fmaf(xv[t][0], wv[j][0], acc[t][j]);
                acc[t][j] = fmaf(xv[t][1], wv[j][1], acc[t][j]);
                acc[t][j] = fmaf(xv[t][2], wv[j][2], acc[t][j]);
                acc[t][j] = fmaf(xv[t][3], wv[j][3], acc[t][j]);
            }
    }

    if (BLEND) {
#pragma unroll
        for (int t = 0; t < NT; ++t) {
            int r = rl + RT * t;
#pragma unroll
            for (int j = 0; j < CJ; ++j) {
                unsigned u = sX[r * KP2 + ((ob + NCT * j) >> 1)];
                float hv = __uint_as_float((ob & 1) ? (u & 0xffff0000u) : (u << 16));
                acc[t][j] = (1.0f - beta) * hv + beta * acc[t][j];
            }
        }
    }

#pragma unroll
    for (int t = 0; t < NT; ++t) {
        const int n = nbase + rl + RT * t;
        const bool valid = n < N_NODES;
#pragma unroll
        for (int j = 0; j < CJ; ++j) {
            float p = __shfl_xor(acc[t][j], 1);
            if (valid && !(ob & 1))
                outb[(size_t)n * (C / 2) + ((ob + NCT * j) >> 1)] = packbf(acc[t][j], p);
        }
    }

    if (H0OUT) {
        for (int i = tid; i < RPB * (C / 2); i += 256) {
            int r = i / (C / 2), c2 = i - r * (C / 2);
            int n = nbase + r;
            if (n < N_NODES) h0n[(size_t)n * (C / 2) + c2] = sX[r * KP2 + c2];
        }
    }

    if (STATS) {
#pragma unroll
        for (int j = 0; j < CJ; ++j) {
            float s = 0.0f, q = 0.0f;
#pragma unroll
            for (int t = 0; t < NT; ++t) { s += acc[t][j]; q += acc[t][j] * acc[t][j]; }
#pragma unroll
            for (int m = NCT; m < 64; m <<= 1) { s += __shfl_xor(s, m); q += __shfl_xor(q, m); }
            if ((tid & 63) < NCT) {
                atomicAdd(&osum[ob + NCT * j], s);
                atomicAdd(&osq[ob + NCT * j], q);
            }
        }
    }
}

// ---------------- SpMM v5: bf16 gather table; output fp32 or packed bf16 ----------------

template <int C, bool LAYER, bool STATS, bool PACKO>
__global__ __launch_bounds__(256) void spmm5(
    const uint4* __restrict__ tb, const uint4* __restrict__ h0n,
    const int* __restrict__ row_start, const int2* __restrict__ cw,
    const float* __restrict__ selfw, float* __restrict__ outf, uint4* __restrict__ outp,
    float* __restrict__ osum, float* __restrict__ osq) {
    constexpr int C8 = C / 8;
    __shared__ float ssum[STATS ? C : 1];
    __shared__ float ssq[STATS ? C : 1];
    const int tid = threadIdx.x;
    if (STATS) {
        if (tid < C) { ssum[tid] = 0.0f; ssq[tid] = 0.0f; }
        __syncthreads();
    }
    const int total = N_NODES * C8;
    for (int idx = blockIdx.x * 256 + tid; idx < total; idx += gridDim.x * 256) {
        const int n = idx / C8;
        const int c8 = idx - n * C8;
        const float sw = selfw[n];
        f8 acc = unpack8(tb[idx]);
        acc.lo.x *= sw; acc.lo.y *= sw; acc.lo.z *= sw; acc.lo.w *= sw;
        acc.hi.x *= sw; acc.hi.y *= sw; acc.hi.z *= sw; acc.hi.w *= sw;
        const int rs = row_start[n], re = row_start[n + 1];
        int j = rs;
        for (; j + 3 < re; j += 4) {
            int2 e0 = cw[j], e1 = cw[j + 1], e2 = cw[j + 2], e3 = cw[j + 3];
            uint4 p0 = tb[(size_t)e0.x * C8 + c8];
            uint4 p1 = tb[(size_t)e1.x * C8 + c8];
            uint4 p2 = tb[(size_t)e2.x * C8 + c8];
            uint4 p3 = tb[(size_t)e3.x * C8 + c8];
            float w0 = __int_as_float(e0.y), w1 = __int_as_float(e1.y);
            float w2 = __int_as_float(e2.y), w3 = __int_as_float(e3.y);
            f8 a0 = unpack8(p0), a1 = unpack8(p1), a2 = unpack8(p2), a3 = unpack8(p3);
            acc.lo.x = fmaf(w0, a0.lo.x, acc.lo.x); acc.lo.y = fmaf(w0, a0.lo.y, acc.lo.y);
            acc.lo.z = fmaf(w0, a0.lo.z, acc.lo.z); acc.lo.w = fmaf(w0, a0.lo.w, acc.lo.w);
            acc.hi.x = fmaf(w0, a0.hi.x, acc.hi.x); acc.hi.y = fmaf(w0, a0.hi.y, acc.hi.y);
            acc.hi.z = fmaf(w0, a0.hi.z, acc.hi.z); acc.hi.w = fmaf(w0, a0.hi.w, acc.hi.w);
            acc.lo.x = fmaf(w1, a1.lo.x, acc.lo.x); acc.lo.y = fmaf(w1, a1.lo.y, acc.lo.y);
            acc.lo.z = fmaf(w1, a1.lo.z, acc.lo.z); acc.lo.w = fmaf(w1, a1.lo.w, acc.lo.w);
            acc.hi.x = fmaf(w1, a1.hi.x, acc.hi.x); acc.hi.y = fmaf(w1, a1.hi.y, acc.hi.y);
            acc.hi.z = fmaf(w1, a1.hi.z, acc.hi.z); acc.hi.w = fmaf(w1, a1.hi.w, acc.hi.w);
            acc.lo.x = fmaf(w2, a2.lo.x, acc.lo.x); acc.lo.y = fmaf(w2, a2.lo.y, acc.lo.y);
            acc.lo.z = fmaf(w2, a2.lo.z, acc.lo.z); acc.lo.w = fmaf(w2, a2.lo.w, acc.lo.w);
            acc.hi.x = fmaf(w2, a2.hi.x, acc.hi.x); acc.hi.y = fmaf(w2, a2.hi.y, acc.hi.y);
            acc.hi.z = fmaf(w2, a2.hi.z, acc.hi.z); acc.hi.w = fmaf(w2, a2.hi.w, acc.hi.w);
            acc.lo.x = fmaf(w3, a3.lo.x, acc.lo.x); acc.lo.y = fmaf(w3, a3.lo.y, acc.lo.y);
            acc.lo.z = fmaf(w3, a3.lo.z, acc.lo.z); acc.lo.w = fmaf(w3, a3.lo.w, acc.lo.w);
            acc.hi.x = fmaf(w3, a3.hi.x, acc.hi.x); acc.hi.y = fmaf(w3, a3.hi.y, acc.hi.y);
            acc.hi.z = fmaf(w3, a3.hi.z, acc.hi.z); acc.hi.w = fmaf(w3, a3.hi.w, acc.hi.w);
        }
        for (; j < re; ++j) {
            int2 e0 = cw[j];
            uint4 p0 = tb[(size_t)e0.x * C8 + c8];
            float w0 = __int_as_float(e0.y);
            f8 a0 = unpack8(p0);
            acc.lo.x = fmaf(w0, a0.lo.x, acc.lo.x); acc.lo.y = fmaf(w0, a0.lo.y, acc.lo.y);
            acc.lo.z = fmaf(w0, a0.lo.z, acc.lo.z); acc.lo.w = fmaf(w0, a0.lo.w, acc.lo.w);
            acc.hi.x = fmaf(w0, a0.hi.x, acc.hi.x); acc.hi.y = fmaf(w0, a0.hi.y, acc.hi.y);
            acc.hi.z = fmaf(w0, a0.hi.z, acc.hi.z); acc.hi.w = fmaf(w0, a0.hi.w, acc.hi.w);
        }
        if (LAYER) {
            f8 h0 = unpack8(h0n[idx]);
            acc.lo.x = 0.9f * acc.lo.x + 0.1f * h0.lo.x;
            acc.lo.y = 0.9f * acc.lo.y + 0.1f * h0.lo.y;
            acc.lo.z = 0.9f * acc.lo.z + 0.1f * h0.lo.z;
            acc.lo.w = 0.9f * acc.lo.w + 0.1f * h0.lo.w;
            acc.hi.x = 0.9f * acc.hi.x + 0.1f * h0.hi.x;
            acc.hi.y = 0.9f * acc.hi.y + 0.1f * h0.hi.y;
            acc.hi.z = 0.9f * acc.hi.z + 0.1f * h0.hi.z;
            acc.hi.w = 0.9f * acc.hi.w + 0.1f * h0.hi.w;
        }
        if (PACKO) {
            uint4 pk;
            pk.x = packbf(acc.lo.x, acc.lo.y); pk.y = packbf(acc.lo.z, acc.lo.w);
            pk.z = packbf(acc.hi.x, acc.hi.y); pk.w = packbf(acc.hi.z, acc.hi.w);
            outp[idx] = pk;
        } else {
            float* op = outf + (size_t)n * C + c8 * 8;
            *(float4*)op = acc.lo;
            *(float4*)(op + 4) = acc.hi;
        }
        if (STATS) {
            int c = c8 * 8;
            atomicAdd(&ssum[c + 0], acc.lo.x); atomicAdd(&ssq[c + 0], acc.lo.x * acc.lo.x);
            atomicAdd(&ssum[c + 1], acc.lo.y); atomicAdd(&ssq[c + 1], acc.lo.y * acc.lo.y);
            atomicAdd(&ssum[c + 2], acc.lo.z); atomicAdd(&ssq[c + 2], acc.lo.z * acc.lo.z);
            atomicAdd(&ssum[c + 3], acc.lo.w); atomicAdd(&ssq[c + 3], acc.lo.w * acc.lo.w);
            atomicAdd(&ssum[c + 4], acc.hi.x); atomicAdd(&ssq[c + 4], acc.hi.x * acc.hi.x);
            atomicAdd(&ssum[c + 5], acc.hi.y); atomicAdd(&ssq[c + 5], acc.hi.y * acc.hi.y);
            atomicAdd(&ssum[c + 6], acc.hi.z); atomicAdd(&ssq[c + 6], acc.hi.z * acc.hi.z);
            atomicAdd(&ssum[c + 7], acc.hi.w); atomicAdd(&ssq[c + 7], acc.hi.w * acc.hi.w);
        }
    }
    if (STATS) {
        __syncthreads();
        if (tid < C) {
            atomicAdd(&osum[tid], ssum[tid]);
            atomicAdd(&osq[tid], ssq[tid]);
        }
    }
}

// ---------------- launch ----------------

extern "C" void kernel_launch(void* const* d_in, const int* in_sizes, int n_in,
                              void* d_out, int out_size, void* d_ws, size_t ws_size,
                              hipStream_t stream) {
    const float* x  = (const float*)d_in[0];
    const int*   ei = (const int*)d_in[1];
    const float* W0 = (const float*)d_in[2];
    const float* W1 = (const float*)d_in[3];
    const float* W2 = (const float*)d_in[4];
    const float* W3 = (const float*)d_in[5];
    float* out = (float*)d_out;

    char* w = (char*)d_ws;
    auto alloc = [&](size_t bytes) {
        void* p = (void*)w;
        w += (bytes + 255) & ~(size_t)255;
        return p;
    };
    int*      cnt       = (int*)alloc(N_NODES * 4);
    int*      row_start = (int*)alloc((N_NODES + 1) * 4);
    int*      fillp     = (int*)alloc(N_NODES * 4);
    int2*     cw        = (int2*)alloc((size_t)N_EDGES * 8);
    float*    dinv      = (float*)alloc(N_NODES * 4);
    float*    selfw     = (float*)alloc(N_NODES * 4);
    unsigned* g0b       = (unsigned*)alloc((size_t)N_NODES * (HID_CH / 2) * 4);
    unsigned* sb        = (unsigned*)alloc((size_t)N_NODES * (HID_CH / 2) * 4);
    unsigned* tb        = (unsigned*)alloc((size_t)N_NODES * (HID_CH / 2) * 4);
    unsigned* h0n       = (unsigned*)alloc((size_t)N_NODES * (HID_CH / 2) * 4);
    float*    stats     = (float*)alloc(6 * HID_CH * 4);
    float*    mu0  = (float*)alloc(HID_CH * 4);
    float*    inv0 = (float*)alloc(HID_CH * 4);
    float*    mu1  = (float*)alloc(HID_CH * 4);
    float*    inv1 = (float*)alloc(HID_CH * 4);
    float*    mu2  = (float*)alloc(HID_CH * 4);
    float*    inv2 = (float*)alloc(HID_CH * 4);
    float* sums0 = stats,              * sq0 = stats + HID_CH;
    float* sums1 = stats + 2 * HID_CH, * sq1 = stats + 3 * HID_CH;
    float* sums2 = stats + 4 * HID_CH, * sq2 = stats + 5 * HID_CH;

    const int EB = (N_EDGES + 255) / 256;
    const int NB = (N_NODES + 255) / 256;
    const int G64 = (N_NODES + 63) / 64;       // 782 blocks of 64 rows

    hipMemsetAsync(cnt, 0, N_NODES * 4, stream);
    hipMemsetAsync(fillp, 0, N_NODES * 4, stream);
    hipMemsetAsync(stats, 0, 6 * HID_CH * 4, stream);

    count_kernel<<<EB, 256, 0, stream>>>(ei, cnt);
    norm_kernel<<<NB, 256, 0, stream>>>(cnt, dinv, selfw);
    scan_kernel<<<1, 256, 0, stream>>>(cnt, row_start);
    fill_kernel<<<EB, 256, 0, stream>>>(ei, row_start, fillp, dinv, cw);

    // layer 0: g0b = bf16(x @ W0^T) + stats0
    gemm6<IN_CH, HID_CH, 16, 6, 4, false, false, false, true, false>
        <<<G64, 256, 0, stream>>>(x, W0, g0b, nullptr, nullptr, nullptr, sums0, sq0, 0.0f);
    bn_fin<<<1, HID_CH, 0, stream>>>(sums0, sq0, mu0, inv0);

    // layer 1: tb = bf16(blend(hn0, hn0@W1^T, .5)); h0n = bf16(hn0)
    gemm6<HID_CH, HID_CH, 16, 6, 4, true, true, true, false, true>
        <<<G64, 256, 0, stream>>>(g0b, W1, tb, h0n, mu0, inv0, nullptr, nullptr, 0.5f);
    spmm5<HID_CH, true, true, true><<<2344, 256, 0, stream>>>(
        (const uint4*)tb, (const uint4*)h0n, row_start, cw, selfw, nullptr, (uint4*)sb,
        sums1, sq1);
    bn_fin<<<1, HID_CH, 0, stream>>>(sums1, sq1, mu1, inv1);

    // layer 2: tb = bf16(blend(hn1, hn1@W2^T, .25))
    gemm6<HID_CH, HID_CH, 16, 6, 4, true, true, true, false, false>
        <<<G64, 256, 0, stream>>>(sb, W2, tb, nullptr, mu1, inv1, nullptr, nullptr, 0.25f);
    spmm5<HID_CH, true, true, true><<<2344, 256, 0, stream>>>(
        (const uint4*)tb, (const uint4*)h0n, row_start, cw, selfw, nullptr, (uint4*)sb,
        sums2, sq2);
    bn_fin<<<1, HID_CH, 0, stream>>>(sums2, sq2, mu2, inv2);

    // final: tb = bf16(hn2 @ W3^T); out = spmm(tb)
    gemm6<HID_CH, OUT_CH, 8, 5, 2, true, false, true, false, false>
        <<<G64, 256, 0, stream>>>(sb, W3, tb, nullptr, mu2, inv2, nullptr, nullptr, 0.0f);
    spmm5<OUT_CH, false, false, false><<<977, 256, 0, stream>>>(
        (const uint4*)tb, nullptr, row_start, cw, selfw, out, nullptr, nullptr, nullptr);
}

// Round 9
// 595.863 us; speedup vs baseline: 1.0625x; 1.0625x over previous
//
#include <hip/hip_runtime.h>

#define N_NODES 50000
#define N_EDGES 800000
#define IN_CH 128
#define HID_CH 96
#define OUT_CH 40
#define EPS 1e-5f

typedef __attribute__((ext_vector_type(8))) short bf16x8;
typedef __attribute__((ext_vector_type(4))) float f32x4;

// ---------------- bf16 pack/unpack ----------------

__device__ __forceinline__ unsigned packbf(float a, float b) {
    unsigned ua = __float_as_uint(a), ub = __float_as_uint(b);
    ua += 0x7fffu + ((ua >> 16) & 1u);           // RTNE
    ub += 0x7fffu + ((ub >> 16) & 1u);
    return (ua >> 16) | (ub & 0xffff0000u);
}

struct f8 { float4 lo, hi; };

__device__ __forceinline__ f8 unpack8(uint4 v) {
    f8 r;
    r.lo = make_float4(__uint_as_float(v.x << 16), __uint_as_float(v.x & 0xffff0000u),
                       __uint_as_float(v.y << 16), __uint_as_float(v.y & 0xffff0000u));
    r.hi = make_float4(__uint_as_float(v.z << 16), __uint_as_float(v.z & 0xffff0000u),
                       __uint_as_float(v.w << 16), __uint_as_float(v.w & 0xffff0000u));
    return r;
}

__device__ __forceinline__ void up4(uint2 u, float* f) {
    f[0] = __uint_as_float(u.x << 16);
    f[1] = __uint_as_float(u.x & 0xffff0000u);
    f[2] = __uint_as_float(u.y << 16);
    f[3] = __uint_as_float(u.y & 0xffff0000u);
}

// ---------------- CSR build ----------------

__global__ void count_kernel(const int* __restrict__ ei, int* __restrict__ cnt) {
    int e = blockIdx.x * blockDim.x + threadIdx.x;
    if (e >= N_EDGES) return;
    int s = ei[e], d = ei[N_EDGES + e];
    if (s != d) atomicAdd(&cnt[d], 1);
}

__global__ void norm_kernel(const int* __restrict__ cnt, float* __restrict__ dinv,
                            float* __restrict__ selfw) {
    int n = blockIdx.x * blockDim.x + threadIdx.x;
    if (n >= N_NODES) return;
    float deg = (float)(cnt[n] + 1);
    dinv[n]  = rsqrtf(deg);
    selfw[n] = 1.0f / deg;
}

__global__ void scan_kernel(const int* __restrict__ cnt, int* __restrict__ row_start) {
    __shared__ int partial[256];
    const int T = 256;
    int tid = threadIdx.x;
    int seg = (N_NODES + T - 1) / T;
    int s0 = tid * seg;
    int s1 = s0 + seg; if (s1 > N_NODES) s1 = N_NODES;
    int sum = 0;
    for (int i = s0; i < s1; i++) sum += cnt[i];
    partial[tid] = sum;
    __syncthreads();
    if (tid == 0) {
        int acc = 0;
        for (int i = 0; i < T; i++) { int v = partial[i]; partial[i] = acc; acc += v; }
    }
    __syncthreads();
    int acc = partial[tid];
    for (int i = s0; i < s1; i++) { row_start[i] = acc; acc += cnt[i]; }
    if (tid == T - 1) row_start[N_NODES] = acc;
}

__global__ void fill_kernel(const int* __restrict__ ei, const int* __restrict__ row_start,
                            int* __restrict__ fillp, const float* __restrict__ dinv,
                            int2* __restrict__ cw) {
    int e = blockIdx.x * blockDim.x + threadIdx.x;
    if (e >= N_EDGES) return;
    int s = ei[e], d = ei[N_EDGES + e];
    if (s == d) return;
    int p = atomicAdd(&fillp[d], 1);
    int idx = row_start[d] + p;
    cw[idx] = make_int2(s, __float_as_int(dinv[s] * dinv[d]));
}

__global__ void bn_fin(const float* __restrict__ sums, const float* __restrict__ sq,
                       float* __restrict__ mu, float* __restrict__ inv) {
    int c = threadIdx.x;
    if (c >= HID_CH) return;
    float m = sums[c] * (1.0f / N_NODES);
    float v = sq[c] * (1.0f / N_NODES) - m * m;
    mu[c] = m; inv[c] = rsqrtf(v + EPS);
}

// ---------------- GEMM v7: MFMA 16x16x32 bf16 ----------
// Block 256 = 4 waves; block tile 64 rows x CG cols; wave = 16 rows x CG cols.
// Per wave per k-step: 1 A ds_read_b128 + CJ B ds_read_b128 -> CJ MFMA.
// A frag: lane holds row (l&15), k = (l>>4)*8..+7. B frag: col (l&15), same k.
// D frag: col = lane&15, row = (lane>>4)*4 + reg  [m89-verified].
// CG pads C to multiple of 16 (W rows >= C staged as zeros; writes guarded c < C).

template <int K, int C, int CG, bool XBF16, bool BLEND, bool NORMX, bool STATS, bool H0OUT>
__global__ __launch_bounds__(256, 4) void gemm7(
    const void* __restrict__ Xv, const float* __restrict__ W,
    unsigned* __restrict__ outb, unsigned* __restrict__ h0n,
    const float* __restrict__ muin, const float* __restrict__ invin,
    float* __restrict__ osum, float* __restrict__ osq, float beta) {
    constexpr int K4 = K / 4;                   // float4 / uint2 groups per row
    constexpr int KP2 = (K == 128) ? 68 : 52;   // u32 row stride (bank-spread, 16B-aligned)
    constexpr int KS = K / 32;                  // mfma k-steps
    constexpr int CJ = CG / 16;                 // 16-col tiles per wave
    __shared__ unsigned sW[CG * KP2];
    __shared__ unsigned sX[64 * KP2];
    const int tid = threadIdx.x;
    const int lane = tid & 63;
    const int wid = tid >> 6;
    const int nbase = (int)blockIdx.x * 64;
    const float4* W4 = (const float4*)W;

    // stage W (fp32 -> bf16 LDS, zero-pad rows >= C)
    for (int i = tid; i < CG * K4; i += 256) {
        int o = i / K4, k4 = i - o * K4;
        uint2 pk = make_uint2(0u, 0u);
        if (o < C) {
            float4 wv = W4[(size_t)o * K4 + k4];
            pk.x = packbf(wv.x, wv.y); pk.y = packbf(wv.z, wv.w);
        }
        *(uint2*)&sW[o * KP2 + k4 * 2] = pk;
    }
    // stage X (bf16 LDS; BN+ReLU if NORMX; zero-pad rows >= N_NODES)
    for (int i = tid; i < 64 * K4; i += 256) {
        int r = i / K4, k4 = i - r * K4;
        int n = nbase + r;
        float f[4] = {0.f, 0.f, 0.f, 0.f};
        if (n < N_NODES) {
            if (XBF16) {
                uint2 u = *(const uint2*)&((const unsigned*)Xv)[(size_t)n * (K / 2) + k4 * 2];
                up4(u, f);
            } else {
                float4 v = ((const float4*)Xv)[(size_t)n * K4 + k4];
                f[0] = v.x; f[1] = v.y; f[2] = v.z; f[3] = v.w;
            }
        }
        if (NORMX) {
            float4 m  = *(const float4*)&muin[k4 * 4];
            float4 iv = *(const float4*)&invin[k4 * 4];
            f[0] = fmaxf((f[0] - m.x) * iv.x, 0.0f);
            f[1] = fmaxf((f[1] - m.y) * iv.y, 0.0f);
            f[2] = fmaxf((f[2] - m.z) * iv.z, 0.0f);
            f[3] = fmaxf((f[3] - m.w) * iv.w, 0.0f);
        }
        uint2 pk; pk.x = packbf(f[0], f[1]); pk.y = packbf(f[2], f[3]);
        *(uint2*)&sX[r * KP2 + k4 * 2] = pk;
    }
    __syncthreads();

    const int r0 = wid * 16;
    const int l15 = lane & 15;
    const int koff = (lane >> 4) * 4;           // u32 offset: 8 bf16 per lane
    f32x4 acc[CJ];
#pragma unroll
    for (int j = 0; j < CJ; ++j) acc[j] = (f32x4){0.f, 0.f, 0.f, 0.f};

#pragma unroll
    for (int kk = 0; kk < KS; ++kk) {
        bf16x8 a = *(const bf16x8*)&sX[(r0 + l15) * KP2 + koff + kk * 16];
        bf16x8 b[CJ];
#pragma unroll
        for (int j = 0; j < CJ; ++j)
            b[j] = *(const bf16x8*)&sW[(j * 16 + l15) * KP2 + koff + kk * 16];
#pragma unroll
        for (int j = 0; j < CJ; ++j)
            acc[j] = __builtin_amdgcn_mfma_f32_16x16x32_bf16(a, b[j], acc[j], 0, 0, 0);
    }

    // epilogue: D lane holds col c = j*16 + (lane&15), rows r0 + (lane>>4)*4 + q
    const int orow0 = r0 + ((lane >> 4) << 2);
#pragma unroll
    for (int j = 0; j < CJ; ++j) {
        const int c = j * 16 + l15;
#pragma unroll
        for (int q = 0; q < 4; ++q) {
            float v = acc[j][q];
            const int row = orow0 + q;
            if (BLEND) {
                unsigned u = sX[row * KP2 + (c >> 1)];
                float hv = __uint_as_float((c & 1) ? (u & 0xffff0000u) : (u << 16));
                v = (1.0f - beta) * hv + beta * v;
            }
            float p = __shfl_xor(v, 1);
            const int n = nbase + row;
            if (!(lane & 1) && n < N_NODES && c < C)
                outb[(size_t)n * (C / 2) + (c >> 1)] = packbf(v, p);
        }
        if (STATS) {
            float s = acc[j][0] + acc[j][1] + acc[j][2] + acc[j][3];
            float q2 = acc[j][0] * acc[j][0] + acc[j][1] * acc[j][1] +
                       acc[j][2] * acc[j][2] + acc[j][3] * acc[j][3];
            s  += __shfl_xor(s, 16);  s  += __shfl_xor(s, 32);
            q2 += __shfl_xor(q2, 16); q2 += __shfl_xor(q2, 32);
            if (lane < 16 && (j * 16 + lane) < C) {
                atomicAdd(&osum[j * 16 + lane], s);
                atomicAdd(&osq[j * 16 + lane], q2);
            }
        }
    }

    if (H0OUT) {
        for (int i = tid; i < 64 * (C / 2); i += 256) {
            int r = i / (C / 2), c2 = i - r * (C / 2);
            int n = nbase + r;
            if (n < N_NODES) h0n[(size_t)n * (C / 2) + c2] = sX[r * KP2 + c2];
        }
    }
}

// ---------------- SpMM v5: bf16 gather table; output fp32 or packed bf16 ----------------

template <int C, bool LAYER, bool STATS, bool PACKO>
__global__ __launch_bounds__(256) void spmm5(
    const uint4* __restrict__ tb, const uint4* __restrict__ h0n,
    const int* __restrict__ row_start, const int2* __restrict__ cw,
    const float* __restrict__ selfw, float* __restrict__ outf, uint4* __restrict__ outp,
    float* __restrict__ osum, float* __restrict__ osq) {
    constexpr int C8 = C / 8;
    __shared__ float ssum[STATS ? C : 1];
    __shared__ float ssq[STATS ? C : 1];
    const int tid = threadIdx.x;
    if (STATS) {
        if (tid < C) { ssum[tid] = 0.0f; ssq[tid] = 0.0f; }
        __syncthreads();
    }
    const int total = N_NODES * C8;
    for (int idx = blockIdx.x * 256 + tid; idx < total; idx += gridDim.x * 256) {
        const int n = idx / C8;
        const int c8 = idx - n * C8;
        const float sw = selfw[n];
        f8 acc = unpack8(tb[idx]);
        acc.lo.x *= sw; acc.lo.y *= sw; acc.lo.z *= sw; acc.lo.w *= sw;
        acc.hi.x *= sw; acc.hi.y *= sw; acc.hi.z *= sw; acc.hi.w *= sw;
        const int rs = row_start[n], re = row_start[n + 1];
        int j = rs;
        for (; j + 3 < re; j += 4) {
            int2 e0 = cw[j], e1 = cw[j + 1], e2 = cw[j + 2], e3 = cw[j + 3];
            uint4 p0 = tb[(size_t)e0.x * C8 + c8];
            uint4 p1 = tb[(size_t)e1.x * C8 + c8];
            uint4 p2 = tb[(size_t)e2.x * C8 + c8];
            uint4 p3 = tb[(size_t)e3.x * C8 + c8];
            float w0 = __int_as_float(e0.y), w1 = __int_as_float(e1.y);
            float w2 = __int_as_float(e2.y), w3 = __int_as_float(e3.y);
            f8 a0 = unpack8(p0), a1 = unpack8(p1), a2 = unpack8(p2), a3 = unpack8(p3);
            acc.lo.x = fmaf(w0, a0.lo.x, acc.lo.x); acc.lo.y = fmaf(w0, a0.lo.y, acc.lo.y);
            acc.lo.z = fmaf(w0, a0.lo.z, acc.lo.z); acc.lo.w = fmaf(w0, a0.lo.w, acc.lo.w);
            acc.hi.x = fmaf(w0, a0.hi.x, acc.hi.x); acc.hi.y = fmaf(w0, a0.hi.y, acc.hi.y);
            acc.hi.z = fmaf(w0, a0.hi.z, acc.hi.z); acc.hi.w = fmaf(w0, a0.hi.w, acc.hi.w);
            acc.lo.x = fmaf(w1, a1.lo.x, acc.lo.x); acc.lo.y = fmaf(w1, a1.lo.y, acc.lo.y);
            acc.lo.z = fmaf(w1, a1.lo.z, acc.lo.z); acc.lo.w = fmaf(w1, a1.lo.w, acc.lo.w);
            acc.hi.x = fmaf(w1, a1.hi.x, acc.hi.x); acc.hi.y = fmaf(w1, a1.hi.y, acc.hi.y);
            acc.hi.z = fmaf(w1, a1.hi.z, acc.hi.z); acc.hi.w = fmaf(w1, a1.hi.w, acc.hi.w);
            acc.lo.x = fmaf(w2, a2.lo.x, acc.lo.x); acc.lo.y = fmaf(w2, a2.lo.y, acc.lo.y);
            acc.lo.z = fmaf(w2, a2.lo.z, acc.lo.z); acc.lo.w = fmaf(w2, a2.lo.w, acc.lo.w);
            acc.hi.x = fmaf(w2, a2.hi.x, acc.hi.x); acc.hi.y = fmaf(w2, a2.hi.y, acc.hi.y);
            acc.hi.z = fmaf(w2, a2.hi.z, acc.hi.z); acc.hi.w = fmaf(w2, a2.hi.w, acc.hi.w);
            acc.lo.x = fmaf(w3, a3.lo.x, acc.lo.x); acc.lo.y = fmaf(w3, a3.lo.y, acc.lo.y);
            acc.lo.z = fmaf(w3, a3.lo.z, acc.lo.z); acc.lo.w = fmaf(w3, a3.lo.w, acc.lo.w);
            acc.hi.x = fmaf(w3, a3.hi.x, acc.hi.x); acc.hi.y = fmaf(w3, a3.hi.y, acc.hi.y);
            acc.hi.z = fmaf(w3, a3.hi.z, acc.hi.z); acc.hi.w = fmaf(w3, a3.hi.w, acc.hi.w);
        }
        for (; j < re; ++j) {
            int2 e0 = cw[j];
            uint4 p0 = tb[(size_t)e0.x * C8 + c8];
            float w0 = __int_as_float(e0.y);
            f8 a0 = unpack8(p0);
            acc.lo.x = fmaf(w0, a0.lo.x, acc.lo.x); acc.lo.y = fmaf(w0, a0.lo.y, acc.lo.y);
            acc.lo.z = fmaf(w0, a0.lo.z, acc.lo.z); acc.lo.w = fmaf(w0, a0.lo.w, acc.lo.w);
            acc.hi.x = fmaf(w0, a0.hi.x, acc.hi.x); acc.hi.y = fmaf(w0, a0.hi.y, acc.hi.y);
            acc.hi.z = fmaf(w0, a0.hi.z, acc.hi.z); acc.hi.w = fmaf(w0, a0.hi.w, acc.hi.w);
        }
        if (LAYER) {
            f8 h0 = unpack8(h0n[idx]);
            acc.lo.x = 0.9f * acc.lo.x + 0.1f * h0.lo.x;
            acc.lo.y = 0.9f * acc.lo.y + 0.1f * h0.lo.y;
            acc.lo.z = 0.9f * acc.lo.z + 0.1f * h0.lo.z;
            acc.lo.w = 0.9f * acc.lo.w + 0.1f * h0.lo.w;
            acc.hi.x = 0.9f * acc.hi.x + 0.1f * h0.hi.x;
            acc.hi.y = 0.9f * acc.hi.y + 0.1f * h0.hi.y;
            acc.hi.z = 0.9f * acc.hi.z + 0.1f * h0.hi.z;
            acc.hi.w = 0.9f * acc.hi.w + 0.1f * h0.hi.w;
        }
        if (PACKO) {
            uint4 pk;
            pk.x = packbf(acc.lo.x, acc.lo.y); pk.y = packbf(acc.lo.z, acc.lo.w);
            pk.z = packbf(acc.hi.x, acc.hi.y); pk.w = packbf(acc.hi.z, acc.hi.w);
            outp[idx] = pk;
        } else {
            float* op = outf + (size_t)n * C + c8 * 8;
            *(float4*)op = acc.lo;
            *(float4*)(op + 4) = acc.hi;
        }
        if (STATS) {
            int c = c8 * 8;
            atomicAdd(&ssum[c + 0], acc.lo.x); atomicAdd(&ssq[c + 0], acc.lo.x * acc.lo.x);
            atomicAdd(&ssum[c + 1], acc.lo.y); atomicAdd(&ssq[c + 1], acc.lo.y * acc.lo.y);
            atomicAdd(&ssum[c + 2], acc.lo.z); atomicAdd(&ssq[c + 2], acc.lo.z * acc.lo.z);
            atomicAdd(&ssum[c + 3], acc.lo.w); atomicAdd(&ssq[c + 3], acc.lo.w * acc.lo.w);
            atomicAdd(&ssum[c + 4], acc.hi.x); atomicAdd(&ssq[c + 4], acc.hi.x * acc.hi.x);
            atomicAdd(&ssum[c + 5], acc.hi.y); atomicAdd(&ssq[c + 5], acc.hi.y * acc.hi.y);
            atomicAdd(&ssum[c + 6], acc.hi.z); atomicAdd(&ssq[c + 6], acc.hi.z * acc.hi.z);
            atomicAdd(&ssum[c + 7], acc.hi.w); atomicAdd(&ssq[c + 7], acc.hi.w * acc.hi.w);
        }
    }
    if (STATS) {
        __syncthreads();
        if (tid < C) {
            atomicAdd(&osum[tid], ssum[tid]);
            atomicAdd(&osq[tid], ssq[tid]);
        }
    }
}

// ---------------- launch ----------------

extern "C" void kernel_launch(void* const* d_in, const int* in_sizes, int n_in,
                              void* d_out, int out_size, void* d_ws, size_t ws_size,
                              hipStream_t stream) {
    const float* x  = (const float*)d_in[0];
    const int*   ei = (const int*)d_in[1];
    const float* W0 = (const float*)d_in[2];
    const float* W1 = (const float*)d_in[3];
    const float* W2 = (const float*)d_in[4];
    const float* W3 = (const float*)d_in[5];
    float* out = (float*)d_out;

    char* w = (char*)d_ws;
    auto alloc = [&](size_t bytes) {
        void* p = (void*)w;
        w += (bytes + 255) & ~(size_t)255;
        return p;
    };
    int*      cnt       = (int*)alloc(N_NODES * 4);
    int*      row_start = (int*)alloc((N_NODES + 1) * 4);
    int*      fillp     = (int*)alloc(N_NODES * 4);
    int2*     cw        = (int2*)alloc((size_t)N_EDGES * 8);
    float*    dinv      = (float*)alloc(N_NODES * 4);
    float*    selfw     = (float*)alloc(N_NODES * 4);
    unsigned* g0b       = (unsigned*)alloc((size_t)N_NODES * (HID_CH / 2) * 4);
    unsigned* sb        = (unsigned*)alloc((size_t)N_NODES * (HID_CH / 2) * 4);
    unsigned* tb        = (unsigned*)alloc((size_t)N_NODES * (HID_CH / 2) * 4);
    unsigned* h0n       = (unsigned*)alloc((size_t)N_NODES * (HID_CH / 2) * 4);
    float*    stats     = (float*)alloc(6 * HID_CH * 4);
    float*    mu0  = (float*)alloc(HID_CH * 4);
    float*    inv0 = (float*)alloc(HID_CH * 4);
    float*    mu1  = (float*)alloc(HID_CH * 4);
    float*    inv1 = (float*)alloc(HID_CH * 4);
    float*    mu2  = (float*)alloc(HID_CH * 4);
    float*    inv2 = (float*)alloc(HID_CH * 4);
    float* sums0 = stats,              * sq0 = stats + HID_CH;
    float* sums1 = stats + 2 * HID_CH, * sq1 = stats + 3 * HID_CH;
    float* sums2 = stats + 4 * HID_CH, * sq2 = stats + 5 * HID_CH;

    const int EB = (N_EDGES + 255) / 256;
    const int NB = (N_NODES + 255) / 256;
    const int G64 = (N_NODES + 63) / 64;       // 782 blocks of 64 rows

    hipMemsetAsync(cnt, 0, N_NODES * 4, stream);
    hipMemsetAsync(fillp, 0, N_NODES * 4, stream);
    hipMemsetAsync(stats, 0, 6 * HID_CH * 4, stream);

    count_kernel<<<EB, 256, 0, stream>>>(ei, cnt);
    norm_kernel<<<NB, 256, 0, stream>>>(cnt, dinv, selfw);
    scan_kernel<<<1, 256, 0, stream>>>(cnt, row_start);
    fill_kernel<<<EB, 256, 0, stream>>>(ei, row_start, fillp, dinv, cw);

    // layer 0: g0b = bf16(x @ W0^T) + stats0
    gemm7<IN_CH, HID_CH, 96, false, false, false, true, false>
        <<<G64, 256, 0, stream>>>(x, W0, g0b, nullptr, nullptr, nullptr, sums0, sq0, 0.0f);
    bn_fin<<<1, HID_CH, 0, stream>>>(sums0, sq0, mu0, inv0);

    // layer 1: tb = bf16(blend(hn0, hn0@W1^T, .5)); h0n = bf16(hn0)
    gemm7<HID_CH, HID_CH, 96, true, true, true, false, true>
        <<<G64, 256, 0, stream>>>(g0b, W1, tb, h0n, mu0, inv0, nullptr, nullptr, 0.5f);
    spmm5<HID_CH, true, true, true><<<2344, 256, 0, stream>>>(
        (const uint4*)tb, (const uint4*)h0n, row_start, cw, selfw, nullptr, (uint4*)sb,
        sums1, sq1);
    bn_fin<<<1, HID_CH, 0, stream>>>(sums1, sq1, mu1, inv1);

    // layer 2: tb = bf16(blend(hn1, hn1@W2^T, .25))
    gemm7<HID_CH, HID_CH, 96, true, true, true, false, false>
        <<<G64, 256, 0, stream>>>(sb, W2, tb, nullptr, mu1, inv1, nullptr, nullptr, 0.25f);
    spmm5<HID_CH, true, true, true><<<2344, 256, 0, stream>>>(
        (const uint4*)tb, (const uint4*)h0n, row_start, cw, selfw, nullptr, (uint4*)sb,
        sums2, sq2);
    bn_fin<<<1, HID_CH, 0, stream>>>(sums2, sq2, mu2, inv2);

    // final: tb = bf16(hn2 @ W3^T); out = spmm(tb)
    gemm7<HID_CH, OUT_CH, 48, true, false, true, false, false>
        <<<G64, 256, 0, stream>>>(sb, W3, tb, nullptr, mu2, inv2, nullptr, nullptr, 0.0f);
    spmm5<OUT_CH, false, false, false><<<977, 256, 0, stream>>>(
        (const uint4*)tb, nullptr, row_start, cw, selfw, out, nullptr, nullptr, nullptr);
}

// Round 10
// 477.784 us; speedup vs baseline: 1.3250x; 1.2471x over previous
//
#include <hip/hip_runtime.h>

#define N_NODES 50000
#define N_EDGES 800000
#define IN_CH 128
#define HID_CH 96
#define OUT_CH 40
#define EPS 1e-5f
#define NREP 32          // stats replication (breaks atomic same-sector serialization)

typedef __attribute__((ext_vector_type(8))) short bf16x8;
typedef __attribute__((ext_vector_type(4))) float f32x4;

// ---------------- bf16 pack/unpack ----------------

__device__ __forceinline__ unsigned packbf(float a, float b) {
    unsigned ua = __float_as_uint(a), ub = __float_as_uint(b);
    ua += 0x7fffu + ((ua >> 16) & 1u);           // RTNE
    ub += 0x7fffu + ((ub >> 16) & 1u);
    return (ua >> 16) | (ub & 0xffff0000u);
}

struct f8 { float4 lo, hi; };

__device__ __forceinline__ f8 unpack8(uint4 v) {
    f8 r;
    r.lo = make_float4(__uint_as_float(v.x << 16), __uint_as_float(v.x & 0xffff0000u),
                       __uint_as_float(v.y << 16), __uint_as_float(v.y & 0xffff0000u));
    r.hi = make_float4(__uint_as_float(v.z << 16), __uint_as_float(v.z & 0xffff0000u),
                       __uint_as_float(v.w << 16), __uint_as_float(v.w & 0xffff0000u));
    return r;
}

__device__ __forceinline__ void up4(uint2 u, float* f) {
    f[0] = __uint_as_float(u.x << 16);
    f[1] = __uint_as_float(u.x & 0xffff0000u);
    f[2] = __uint_as_float(u.y << 16);
    f[3] = __uint_as_float(u.y & 0xffff0000u);
}

// ---------------- CSR build ----------------

__global__ void count_kernel(const int* __restrict__ ei, int* __restrict__ cnt) {
    int e = blockIdx.x * blockDim.x + threadIdx.x;
    if (e >= N_EDGES) return;
    int s = ei[e], d = ei[N_EDGES + e];
    if (s != d) atomicAdd(&cnt[d], 1);
}

__global__ void norm_kernel(const int* __restrict__ cnt, float* __restrict__ dinv,
                            float* __restrict__ selfw) {
    int n = blockIdx.x * blockDim.x + threadIdx.x;
    if (n >= N_NODES) return;
    float deg = (float)(cnt[n] + 1);
    dinv[n]  = rsqrtf(deg);
    selfw[n] = 1.0f / deg;
}

__global__ void scan_kernel(const int* __restrict__ cnt, int* __restrict__ row_start) {
    __shared__ int partial[256];
    const int T = 256;
    int tid = threadIdx.x;
    int seg = (N_NODES + T - 1) / T;
    int s0 = tid * seg;
    int s1 = s0 + seg; if (s1 > N_NODES) s1 = N_NODES;
    int sum = 0;
    for (int i = s0; i < s1; i++) sum += cnt[i];
    partial[tid] = sum;
    __syncthreads();
    if (tid == 0) {
        int acc = 0;
        for (int i = 0; i < T; i++) { int v = partial[i]; partial[i] = acc; acc += v; }
    }
    __syncthreads();
    int acc = partial[tid];
    for (int i = s0; i < s1; i++) { row_start[i] = acc; acc += cnt[i]; }
    if (tid == T - 1) row_start[N_NODES] = acc;
}

__global__ void fill_kernel(const int* __restrict__ ei, const int* __restrict__ row_start,
                            int* __restrict__ fillp, const float* __restrict__ dinv,
                            int2* __restrict__ cw) {
    int e = blockIdx.x * blockDim.x + threadIdx.x;
    if (e >= N_EDGES) return;
    int s = ei[e], d = ei[N_EDGES + e];
    if (s == d) return;
    int p = atomicAdd(&fillp[d], 1);
    int idx = row_start[d] + p;
    cw[idx] = make_int2(s, __float_as_int(dinv[s] * dinv[d]));
}

// stat buffer layout: [NREP][2][HID_CH]  (sum copy k at k*192 + c, sq at k*192 + 96 + c)
__global__ void bn_fin(const float* __restrict__ stat, float* __restrict__ mu,
                       float* __restrict__ inv) {
    int c = threadIdx.x;
    if (c >= HID_CH) return;
    float s = 0.0f, q = 0.0f;
    for (int k = 0; k < NREP; k++) {
        s += stat[k * 2 * HID_CH + c];
        q += stat[k * 2 * HID_CH + HID_CH + c];
    }
    float m = s * (1.0f / N_NODES);
    float v = q * (1.0f / N_NODES) - m * m;
    mu[c] = m; inv[c] = rsqrtf(v + EPS);
}

// ---------------- GEMM v7b: MFMA 16x16x32 bf16; stats via LDS-reduce + replicated atomics --
// Block 256 = 4 waves; block tile 64 rows x CG cols; wave = 16 rows x CG cols.
// A frag: lane holds row (l&15), k = (l>>4)*8..+7. B frag: col (l&15), same k.
// D frag: col = lane&15, row = (lane>>4)*4 + reg  [m89-verified].

template <int K, int C, int CG, bool XBF16, bool BLEND, bool NORMX, bool STATS, bool H0OUT>
__global__ __launch_bounds__(256, 4) void gemm7(
    const void* __restrict__ Xv, const float* __restrict__ W,
    unsigned* __restrict__ outb, unsigned* __restrict__ h0n,
    const float* __restrict__ muin, const float* __restrict__ invin,
    float* __restrict__ stat, float beta) {
    constexpr int K4 = K / 4;                   // float4 / uint2 groups per row
    constexpr int KP2 = (K == 128) ? 68 : 52;   // u32 row stride (bank-spread, 16B-aligned)
    constexpr int KS = K / 32;                  // mfma k-steps
    constexpr int CJ = CG / 16;                 // 16-col tiles per wave
    __shared__ unsigned sW[CG * KP2];
    __shared__ unsigned sX[64 * KP2];
    __shared__ float sstat[STATS ? CG * 4 : 1];   // per-wave column sums
    __shared__ float sstatq[STATS ? CG * 4 : 1];
    const int tid = threadIdx.x;
    const int lane = tid & 63;
    const int wid = tid >> 6;
    const int nbase = (int)blockIdx.x * 64;
    const float4* W4 = (const float4*)W;

    // stage W (fp32 -> bf16 LDS, zero-pad rows >= C)
    for (int i = tid; i < CG * K4; i += 256) {
        int o = i / K4, k4 = i - o * K4;
        uint2 pk = make_uint2(0u, 0u);
        if (o < C) {
            float4 wv = W4[(size_t)o * K4 + k4];
            pk.x = packbf(wv.x, wv.y); pk.y = packbf(wv.z, wv.w);
        }
        *(uint2*)&sW[o * KP2 + k4 * 2] = pk;
    }
    // stage X (bf16 LDS; BN+ReLU if NORMX; zero-pad rows >= N_NODES)
    for (int i = tid; i < 64 * K4; i += 256) {
        int r = i / K4, k4 = i - r * K4;
        int n = nbase + r;
        float f[4] = {0.f, 0.f, 0.f, 0.f};
        if (n < N_NODES) {
            if (XBF16) {
                uint2 u = *(const uint2*)&((const unsigned*)Xv)[(size_t)n * (K / 2) + k4 * 2];
                up4(u, f);
            } else {
                float4 v = ((const float4*)Xv)[(size_t)n * K4 + k4];
                f[0] = v.x; f[1] = v.y; f[2] = v.z; f[3] = v.w;
            }
        }
        if (NORMX) {
            float4 m  = *(const float4*)&muin[k4 * 4];
            float4 iv = *(const float4*)&invin[k4 * 4];
            f[0] = fmaxf((f[0] - m.x) * iv.x, 0.0f);
            f[1] = fmaxf((f[1] - m.y) * iv.y, 0.0f);
            f[2] = fmaxf((f[2] - m.z) * iv.z, 0.0f);
            f[3] = fmaxf((f[3] - m.w) * iv.w, 0.0f);
        }
        uint2 pk; pk.x = packbf(f[0], f[1]); pk.y = packbf(f[2], f[3]);
        *(uint2*)&sX[r * KP2 + k4 * 2] = pk;
    }
    __syncthreads();

    const int r0 = wid * 16;
    const int l15 = lane & 15;
    const int koff = (lane >> 4) * 4;           // u32 offset: 8 bf16 per lane
    f32x4 acc[CJ];
#pragma unroll
    for (int j = 0; j < CJ; ++j) acc[j] = (f32x4){0.f, 0.f, 0.f, 0.f};

#pragma unroll
    for (int kk = 0; kk < KS; ++kk) {
        bf16x8 a = *(const bf16x8*)&sX[(r0 + l15) * KP2 + koff + kk * 16];
        bf16x8 b[CJ];
#pragma unroll
        for (int j = 0; j < CJ; ++j)
            b[j] = *(const bf16x8*)&sW[(j * 16 + l15) * KP2 + koff + kk * 16];
#pragma unroll
        for (int j = 0; j < CJ; ++j)
            acc[j] = __builtin_amdgcn_mfma_f32_16x16x32_bf16(a, b[j], acc[j], 0, 0, 0);
    }

    // epilogue: D lane holds col c = j*16 + (lane&15), rows r0 + (lane>>4)*4 + q
    const int orow0 = r0 + ((lane >> 4) << 2);
#pragma unroll
    for (int j = 0; j < CJ; ++j) {
        const int c = j * 16 + l15;
#pragma unroll
        for (int q = 0; q < 4; ++q) {
            float v = acc[j][q];
            const int row = orow0 + q;
            if (BLEND) {
                unsigned u = sX[row * KP2 + (c >> 1)];
                float hv = __uint_as_float((c & 1) ? (u & 0xffff0000u) : (u << 16));
                v = (1.0f - beta) * hv + beta * v;
            }
            float p = __shfl_xor(v, 1);
            const int n = nbase + row;
            if (!(lane & 1) && n < N_NODES && c < C)
                outb[(size_t)n * (C / 2) + (c >> 1)] = packbf(v, p);
        }
        if (STATS) {
            float s = acc[j][0] + acc[j][1] + acc[j][2] + acc[j][3];
            float q2 = acc[j][0] * acc[j][0] + acc[j][1] * acc[j][1] +
                       acc[j][2] * acc[j][2] + acc[j][3] * acc[j][3];
            s  += __shfl_xor(s, 16);  s  += __shfl_xor(s, 32);
            q2 += __shfl_xor(q2, 16); q2 += __shfl_xor(q2, 32);
            if (lane < 16) {
                sstat[(j * 16 + lane) * 4 + wid] = s;
                sstatq[(j * 16 + lane) * 4 + wid] = q2;
            }
        }
    }

    if (H0OUT) {
        for (int i = tid; i < 64 * (C / 2); i += 256) {
            int r = i / (C / 2), c2 = i - r * (C / 2);
            int n = nbase + r;
            if (n < N_NODES) h0n[(size_t)n * (C / 2) + c2] = sX[r * KP2 + c2];
        }
    }

    if (STATS) {
        __syncthreads();
        if (tid < C) {
            float s = sstat[tid * 4] + sstat[tid * 4 + 1] + sstat[tid * 4 + 2] +
                      sstat[tid * 4 + 3];
            float q = sstatq[tid * 4] + sstatq[tid * 4 + 1] + sstatq[tid * 4 + 2] +
                      sstatq[tid * 4 + 3];
            const int rep = ((int)blockIdx.x & (NREP - 1)) * 2 * HID_CH;
            atomicAdd(&stat[rep + tid], s);
            atomicAdd(&stat[rep + HID_CH + tid], q);
        }
    }
}

// ---------------- SpMM v5b: bf16 gather table; stats into replicated slots ----------------

template <int C, bool LAYER, bool STATS, bool PACKO>
__global__ __launch_bounds__(256) void spmm5(
    const uint4* __restrict__ tb, const uint4* __restrict__ h0n,
    const int* __restrict__ row_start, const int2* __restrict__ cw,
    const float* __restrict__ selfw, float* __restrict__ outf, uint4* __restrict__ outp,
    float* __restrict__ stat) {
    constexpr int C8 = C / 8;
    __shared__ float ssum[STATS ? C : 1];
    __shared__ float ssq[STATS ? C : 1];
    const int tid = threadIdx.x;
    if (STATS) {
        if (tid < C) { ssum[tid] = 0.0f; ssq[tid] = 0.0f; }
        __syncthreads();
    }
    const int total = N_NODES * C8;
    for (int idx = blockIdx.x * 256 + tid; idx < total; idx += gridDim.x * 256) {
        const int n = idx / C8;
        const int c8 = idx - n * C8;
        const float sw = selfw[n];
        f8 acc = unpack8(tb[idx]);
        acc.lo.x *= sw; acc.lo.y *= sw; acc.lo.z *= sw; acc.lo.w *= sw;
        acc.hi.x *= sw; acc.hi.y *= sw; acc.hi.z *= sw; acc.hi.w *= sw;
        const int rs = row_start[n], re = row_start[n + 1];
        int j = rs;
        for (; j + 3 < re; j += 4) {
            int2 e0 = cw[j], e1 = cw[j + 1], e2 = cw[j + 2], e3 = cw[j + 3];
            uint4 p0 = tb[(size_t)e0.x * C8 + c8];
            uint4 p1 = tb[(size_t)e1.x * C8 + c8];
            uint4 p2 = tb[(size_t)e2.x * C8 + c8];
            uint4 p3 = tb[(size_t)e3.x * C8 + c8];
            float w0 = __int_as_float(e0.y), w1 = __int_as_float(e1.y);
            float w2 = __int_as_float(e2.y), w3 = __int_as_float(e3.y);
            f8 a0 = unpack8(p0), a1 = unpack8(p1), a2 = unpack8(p2), a3 = unpack8(p3);
            acc.lo.x = fmaf(w0, a0.lo.x, acc.lo.x); acc.lo.y = fmaf(w0, a0.lo.y, acc.lo.y);
            acc.lo.z = fmaf(w0, a0.lo.z, acc.lo.z); acc.lo.w = fmaf(w0, a0.lo.w, acc.lo.w);
            acc.hi.x = fmaf(w0, a0.hi.x, acc.hi.x); acc.hi.y = fmaf(w0, a0.hi.y, acc.hi.y);
            acc.hi.z = fmaf(w0, a0.hi.z, acc.hi.z); acc.hi.w = fmaf(w0, a0.hi.w, acc.hi.w);
            acc.lo.x = fmaf(w1, a1.lo.x, acc.lo.x); acc.lo.y = fmaf(w1, a1.lo.y, acc.lo.y);
            acc.lo.z = fmaf(w1, a1.lo.z, acc.lo.z); acc.lo.w = fmaf(w1, a1.lo.w, acc.lo.w);
            acc.hi.x = fmaf(w1, a1.hi.x, acc.hi.x); acc.hi.y = fmaf(w1, a1.hi.y, acc.hi.y);
            acc.hi.z = fmaf(w1, a1.hi.z, acc.hi.z); acc.hi.w = fmaf(w1, a1.hi.w, acc.hi.w);
            acc.lo.x = fmaf(w2, a2.lo.x, acc.lo.x); acc.lo.y = fmaf(w2, a2.lo.y, acc.lo.y);
            acc.lo.z = fmaf(w2, a2.lo.z, acc.lo.z); acc.lo.w = fmaf(w2, a2.lo.w, acc.lo.w);
            acc.hi.x = fmaf(w2, a2.hi.x, acc.hi.x); acc.hi.y = fmaf(w2, a2.hi.y, acc.hi.y);
            acc.hi.z = fmaf(w2, a2.hi.z, acc.hi.z); acc.hi.w = fmaf(w2, a2.hi.w, acc.hi.w);
            acc.lo.x = fmaf(w3, a3.lo.x, acc.lo.x); acc.lo.y = fmaf(w3, a3.lo.y, acc.lo.y);
            acc.lo.z = fmaf(w3, a3.lo.z, acc.lo.z); acc.lo.w = fmaf(w3, a3.lo.w, acc.lo.w);
            acc.hi.x = fmaf(w3, a3.hi.x, acc.hi.x); acc.hi.y = fmaf(w3, a3.hi.y, acc.hi.y);
            acc.hi.z = fmaf(w3, a3.hi.z, acc.hi.z); acc.hi.w = fmaf(w3, a3.hi.w, acc.hi.w);
        }
        for (; j < re; ++j) {
            int2 e0 = cw[j];
            uint4 p0 = tb[(size_t)e0.x * C8 + c8];
            float w0 = __int_as_float(e0.y);
            f8 a0 = unpack8(p0);
            acc.lo.x = fmaf(w0, a0.lo.x, acc.lo.x); acc.lo.y = fmaf(w0, a0.lo.y, acc.lo.y);
            acc.lo.z = fmaf(w0, a0.lo.z, acc.lo.z); acc.lo.w = fmaf(w0, a0.lo.w, acc.lo.w);
            acc.hi.x = fmaf(w0, a0.hi.x, acc.hi.x); acc.hi.y = fmaf(w0, a0.hi.y, acc.hi.y);
            acc.hi.z = fmaf(w0, a0.hi.z, acc.hi.z); acc.hi.w = fmaf(w0, a0.hi.w, acc.hi.w);
        }
        if (LAYER) {
            f8 h0 = unpack8(h0n[idx]);
            acc.lo.x = 0.9f * acc.lo.x + 0.1f * h0.lo.x;
            acc.lo.y = 0.9f * acc.lo.y + 0.1f * h0.lo.y;
            acc.lo.z = 0.9f * acc.lo.z + 0.1f * h0.lo.z;
            acc.lo.w = 0.9f * acc.lo.w + 0.1f * h0.lo.w;
            acc.hi.x = 0.9f * acc.hi.x + 0.1f * h0.hi.x;
            acc.hi.y = 0.9f * acc.hi.y + 0.1f * h0.hi.y;
            acc.hi.z = 0.9f * acc.hi.z + 0.1f * h0.hi.z;
            acc.hi.w = 0.9f * acc.hi.w + 0.1f * h0.hi.w;
        }
        if (PACKO) {
            uint4 pk;
            pk.x = packbf(acc.lo.x, acc.lo.y); pk.y = packbf(acc.lo.z, acc.lo.w);
            pk.z = packbf(acc.hi.x, acc.hi.y); pk.w = packbf(acc.hi.z, acc.hi.w);
            outp[idx] = pk;
        } else {
            float* op = outf + (size_t)n * C + c8 * 8;
            *(float4*)op = acc.lo;
            *(float4*)(op + 4) = acc.hi;
        }
        if (STATS) {
            int c = c8 * 8;
            atomicAdd(&ssum[c + 0], acc.lo.x); atomicAdd(&ssq[c + 0], acc.lo.x * acc.lo.x);
            atomicAdd(&ssum[c + 1], acc.lo.y); atomicAdd(&ssq[c + 1], acc.lo.y * acc.lo.y);
            atomicAdd(&ssum[c + 2], acc.lo.z); atomicAdd(&ssq[c + 2], acc.lo.z * acc.lo.z);
            atomicAdd(&ssum[c + 3], acc.lo.w); atomicAdd(&ssq[c + 3], acc.lo.w * acc.lo.w);
            atomicAdd(&ssum[c + 4], acc.hi.x); atomicAdd(&ssq[c + 4], acc.hi.x * acc.hi.x);
            atomicAdd(&ssum[c + 5], acc.hi.y); atomicAdd(&ssq[c + 5], acc.hi.y * acc.hi.y);
            atomicAdd(&ssum[c + 6], acc.hi.z); atomicAdd(&ssq[c + 6], acc.hi.z * acc.hi.z);
            atomicAdd(&ssum[c + 7], acc.hi.w); atomicAdd(&ssq[c + 7], acc.hi.w * acc.hi.w);
        }
    }
    if (STATS) {
        __syncthreads();
        if (tid < C) {
            const int rep = ((int)blockIdx.x & (NREP - 1)) * 2 * HID_CH;
            atomicAdd(&stat[rep + tid], ssum[tid]);
            atomicAdd(&stat[rep + HID_CH + tid], ssq[tid]);
        }
    }
}

// ---------------- launch ----------------

extern "C" void kernel_launch(void* const* d_in, const int* in_sizes, int n_in,
                              void* d_out, int out_size, void* d_ws, size_t ws_size,
                              hipStream_t stream) {
    const float* x  = (const float*)d_in[0];
    const int*   ei = (const int*)d_in[1];
    const float* W0 = (const float*)d_in[2];
    const float* W1 = (const float*)d_in[3];
    const float* W2 = (const float*)d_in[4];
    const float* W3 = (const float*)d_in[5];
    float* out = (float*)d_out;

    char* w = (char*)d_ws;
    auto alloc = [&](size_t bytes) {
        void* p = (void*)w;
        w += (bytes + 255) & ~(size_t)255;
        return p;
    };
    const int STATB = NREP * 2 * HID_CH;   // floats per stat buffer
    int*      cnt       = (int*)alloc(N_NODES * 4);
    int*      row_start = (int*)alloc((N_NODES + 1) * 4);
    int*      fillp     = (int*)alloc(N_NODES * 4);
    int2*     cw        = (int2*)alloc((size_t)N_EDGES * 8);
    float*    dinv      = (float*)alloc(N_NODES * 4);
    float*    selfw     = (float*)alloc(N_NODES * 4);
    unsigned* g0b       = (unsigned*)alloc((size_t)N_NODES * (HID_CH / 2) * 4);
    unsigned* sb        = (unsigned*)alloc((size_t)N_NODES * (HID_CH / 2) * 4);
    unsigned* tb        = (unsigned*)alloc((size_t)N_NODES * (HID_CH / 2) * 4);
    unsigned* h0n       = (unsigned*)alloc((size_t)N_NODES * (HID_CH / 2) * 4);
    float*    stat0     = (float*)alloc(STATB * 4);
    float*    stat1     = (float*)alloc(STATB * 4);
    float*    stat2     = (float*)alloc(STATB * 4);
    float*    mu0  = (float*)alloc(HID_CH * 4);
    float*    inv0 = (float*)alloc(HID_CH * 4);
    float*    mu1  = (float*)alloc(HID_CH * 4);
    float*    inv1 = (float*)alloc(HID_CH * 4);
    float*    mu2  = (float*)alloc(HID_CH * 4);
    float*    inv2 = (float*)alloc(HID_CH * 4);

    const int EB = (N_EDGES + 255) / 256;
    const int NB = (N_NODES + 255) / 256;
    const int G64 = (N_NODES + 63) / 64;       // 782 blocks of 64 rows

    hipMemsetAsync(cnt, 0, N_NODES * 4, stream);
    hipMemsetAsync(fillp, 0, N_NODES * 4, stream);
    hipMemsetAsync(stat0, 0, (size_t)STATB * 3 * 4 + 512, stream);  // stat0..stat2 contiguous

    count_kernel<<<EB, 256, 0, stream>>>(ei, cnt);
    norm_kernel<<<NB, 256, 0, stream>>>(cnt, dinv, selfw);
    scan_kernel<<<1, 256, 0, stream>>>(cnt, row_start);
    fill_kernel<<<EB, 256, 0, stream>>>(ei, row_start, fillp, dinv, cw);

    // layer 0: g0b = bf16(x @ W0^T) + stats0
    gemm7<IN_CH, HID_CH, 96, false, false, false, true, false>
        <<<G64, 256, 0, stream>>>(x, W0, g0b, nullptr, nullptr, nullptr, stat0, 0.0f);
    bn_fin<<<1, HID_CH, 0, stream>>>(stat0, mu0, inv0);

    // layer 1: tb = bf16(blend(hn0, hn0@W1^T, .5)); h0n = bf16(hn0)
    gemm7<HID_CH, HID_CH, 96, true, true, true, false, true>
        <<<G64, 256, 0, stream>>>(g0b, W1, tb, h0n, mu0, inv0, nullptr, 0.5f);
    spmm5<HID_CH, true, true, true><<<2344, 256, 0, stream>>>(
        (const uint4*)tb, (const uint4*)h0n, row_start, cw, selfw, nullptr, (uint4*)sb, stat1);
    bn_fin<<<1, HID_CH, 0, stream>>>(stat1, mu1, inv1);

    // layer 2: tb = bf16(blend(hn1, hn1@W2^T, .25))
    gemm7<HID_CH, HID_CH, 96, true, true, true, false, false>
        <<<G64, 256, 0, stream>>>(sb, W2, tb, nullptr, mu1, inv1, nullptr, 0.25f);
    spmm5<HID_CH, true, true, true><<<2344, 256, 0, stream>>>(
        (const uint4*)tb, (const uint4*)h0n, row_start, cw, selfw, nullptr, (uint4*)sb, stat2);
    bn_fin<<<1, HID_CH, 0, stream>>>(stat2, mu2, inv2);

    // final: tb = bf16(hn2 @ W3^T); out = spmm(tb)
    gemm7<HID_CH, OUT_CH, 48, true, false, true, false, false>
        <<<G64, 256, 0, stream>>>(sb, W3, tb, nullptr, mu2, inv2, nullptr, 0.0f);
    spmm5<OUT_CH, false, false, false><<<977, 256, 0, stream>>>(
        (const uint4*)tb, nullptr, row_start, cw, selfw, out, nullptr, nullptr);
}

// Round 12
// 394.075 us; speedup vs baseline: 1.6065x; 1.2124x over previous
//
#include <hip/hip_runtime.h>

#define N_NODES 50000
#define N_EDGES 800000
#define IN_CH 128
#define HID_CH 96
#define OUT_CH 40
#define EPS 1e-5f
#define NREP 32          // stats replication (breaks atomic same-sector serialization)
#define NBK 196          // scan blocks: ceil(50000/256)

typedef __attribute__((ext_vector_type(8))) short bf16x8;
typedef __attribute__((ext_vector_type(4))) float f32x4;

// ---------------- bf16 pack/unpack ----------------

__device__ __forceinline__ unsigned packbf(float a, float b) {
    unsigned ua = __float_as_uint(a), ub = __float_as_uint(b);
    ua += 0x7fffu + ((ua >> 16) & 1u);           // RTNE
    ub += 0x7fffu + ((ub >> 16) & 1u);
    return (ua >> 16) | (ub & 0xffff0000u);
}

struct f8 { float4 lo, hi; };

__device__ __forceinline__ f8 unpack8(uint4 v) {
    f8 r;
    r.lo = make_float4(__uint_as_float(v.x << 16), __uint_as_float(v.x & 0xffff0000u),
                       __uint_as_float(v.y << 16), __uint_as_float(v.y & 0xffff0000u));
    r.hi = make_float4(__uint_as_float(v.z << 16), __uint_as_float(v.z & 0xffff0000u),
                       __uint_as_float(v.w << 16), __uint_as_float(v.w & 0xffff0000u));
    return r;
}

__device__ __forceinline__ void up4(uint2 u, float* f) {
    f[0] = __uint_as_float(u.x << 16);
    f[1] = __uint_as_float(u.x & 0xffff0000u);
    f[2] = __uint_as_float(u.y << 16);
    f[3] = __uint_as_float(u.y & 0xffff0000u);
}

// ---------------- CSR build ----------------

__global__ void count_kernel(const int* __restrict__ ei, int* __restrict__ cnt) {
    int e = blockIdx.x * blockDim.x + threadIdx.x;
    if (e >= N_EDGES) return;
    int s = ei[e], d = ei[N_EDGES + e];
    if (s != d) atomicAdd(&cnt[d], 1);
}

// phase A: per-block sums of cnt (coalesced)
__global__ void scan_a(const int* __restrict__ cnt, int* __restrict__ bsum) {
    int i = blockIdx.x * 256 + threadIdx.x;
    int v = (i < N_NODES) ? cnt[i] : 0;
#pragma unroll
    for (int d = 1; d < 64; d <<= 1) v += __shfl_xor(v, d);
    __shared__ int ws[4];
    if ((threadIdx.x & 63) == 0) ws[threadIdx.x >> 6] = v;
    __syncthreads();
    if (threadIdx.x == 0) bsum[blockIdx.x] = ws[0] + ws[1] + ws[2] + ws[3];
}

// phase B: exclusive scan of bsum[NBK] (single block), writes row_start[N_NODES]=total
__global__ void scan_b(const int* __restrict__ bsum, int* __restrict__ bexc,
                       int* __restrict__ row_start) {
    const int tid = threadIdx.x;
    const int lane = tid & 63;
    const int wid = tid >> 6;
    int v = (tid < NBK) ? bsum[tid] : 0;
    int inc = v;
#pragma unroll
    for (int d = 1; d < 64; d <<= 1) {
        int t = __shfl_up(inc, d);
        if (lane >= d) inc += t;
    }
    __shared__ int ws[4];
    if (lane == 63) ws[wid] = inc;
    __syncthreads();
    int woff = 0;
    for (int k = 0; k < 4; k++) if (k < wid) woff += ws[k];
    int exc = inc - v + woff;
    if (tid < NBK) bexc[tid] = exc;
    if (tid == NBK - 1) row_start[N_NODES] = exc + v;
}

// phase C: intra-block exclusive scan + block offset -> row_start; fused deg-norm + fillp clear
__global__ void scan_c(const int* __restrict__ cnt, const int* __restrict__ bexc,
                       int* __restrict__ row_start, float* __restrict__ dinv,
                       float* __restrict__ selfw, int* __restrict__ fillp) {
    const int tid = threadIdx.x;
    const int lane = tid & 63;
    const int wid = tid >> 6;
    const int i = blockIdx.x * 256 + tid;
    int v = (i < N_NODES) ? cnt[i] : 0;
    int inc = v;
#pragma unroll
    for (int d = 1; d < 64; d <<= 1) {
        int t = __shfl_up(inc, d);
        if (lane >= d) inc += t;
    }
    __shared__ int ws[4];
    if (lane == 63) ws[wid] = inc;
    __syncthreads();
    int woff = 0;
    for (int k = 0; k < 4; k++) if (k < wid) woff += ws[k];
    if (i < N_NODES) {
        row_start[i] = bexc[blockIdx.x] + woff + inc - v;
        float deg = (float)(v + 1);
        dinv[i]  = rsqrtf(deg);
        selfw[i] = 1.0f / deg;
        fillp[i] = 0;
    }
}

__global__ void fill_kernel(const int* __restrict__ ei, const int* __restrict__ row_start,
                            int* __restrict__ fillp, const float* __restrict__ dinv,
                            int2* __restrict__ cw) {
    int e = blockIdx.x * blockDim.x + threadIdx.x;
    if (e >= N_EDGES) return;
    int s = ei[e], d = ei[N_EDGES + e];
    if (s == d) return;
    int p = atomicAdd(&fillp[d], 1);
    int idx = row_start[d] + p;
    cw[idx] = make_int2(s, __float_as_int(dinv[s] * dinv[d]));
}

// stat buffer layout: [NREP][2][HID_CH]
__global__ void bn_fin(const float* __restrict__ stat, float* __restrict__ mu,
                       float* __restrict__ inv) {
    int c = threadIdx.x;
    if (c >= HID_CH) return;
    float s = 0.0f, q = 0.0f;
    for (int k = 0; k < NREP; k++) {
        s += stat[k * 2 * HID_CH + c];
        q += stat[k * 2 * HID_CH + HID_CH + c];
    }
    float m = s * (1.0f / N_NODES);
    float v = q * (1.0f / N_NODES) - m * m;
    mu[c] = m; inv[c] = rsqrtf(v + EPS);
}

// ---------------- GEMM v7b: MFMA 16x16x32 bf16; stats via LDS-reduce + replicated atomics --

template <int K, int C, int CG, bool XBF16, bool BLEND, bool NORMX, bool STATS, bool H0OUT>
__global__ __launch_bounds__(256, 4) void gemm7(
    const void* __restrict__ Xv, const float* __restrict__ W,
    unsigned* __restrict__ outb, unsigned* __restrict__ h0n,
    const float* __restrict__ muin, const float* __restrict__ invin,
    float* __restrict__ stat, float beta) {
    constexpr int K4 = K / 4;
    constexpr int KP2 = (K == 128) ? 68 : 52;
    constexpr int KS = K / 32;
    constexpr int CJ = CG / 16;
    __shared__ unsigned sW[CG * KP2];
    __shared__ unsigned sX[64 * KP2];
    __shared__ float sstat[STATS ? CG * 4 : 1];
    __shared__ float sstatq[STATS ? CG * 4 : 1];
    const int tid = threadIdx.x;
    const int lane = tid & 63;
    const int wid = tid >> 6;
    const int nbase = (int)blockIdx.x * 64;
    const float4* W4 = (const float4*)W;

    for (int i = tid; i < CG * K4; i += 256) {
        int o = i / K4, k4 = i - o * K4;
        uint2 pk = make_uint2(0u, 0u);
        if (o < C) {
            float4 wv = W4[(size_t)o * K4 + k4];
            pk.x = packbf(wv.x, wv.y); pk.y = packbf(wv.z, wv.w);
        }
        *(uint2*)&sW[o * KP2 + k4 * 2] = pk;
    }
    for (int i = tid; i < 64 * K4; i += 256) {
        int r = i / K4, k4 = i - r * K4;
        int n = nbase + r;
        float f[4] = {0.f, 0.f, 0.f, 0.f};
        if (n < N_NODES) {
            if (XBF16) {
                uint2 u = *(const uint2*)&((const unsigned*)Xv)[(size_t)n * (K / 2) + k4 * 2];
                up4(u, f);
            } else {
                float4 v = ((const float4*)Xv)[(size_t)n * K4 + k4];
                f[0] = v.x; f[1] = v.y; f[2] = v.z; f[3] = v.w;
            }
        }
        if (NORMX) {
            float4 m  = *(const float4*)&muin[k4 * 4];
            float4 iv = *(const float4*)&invin[k4 * 4];
            f[0] = fmaxf((f[0] - m.x) * iv.x, 0.0f);
            f[1] = fmaxf((f[1] - m.y) * iv.y, 0.0f);
            f[2] = fmaxf((f[2] - m.z) * iv.z, 0.0f);
            f[3] = fmaxf((f[3] - m.w) * iv.w, 0.0f);
        }
        uint2 pk; pk.x = packbf(f[0], f[1]); pk.y = packbf(f[2], f[3]);
        *(uint2*)&sX[r * KP2 + k4 * 2] = pk;
    }
    __syncthreads();

    const int r0 = wid * 16;
    const int l15 = lane & 15;
    const int koff = (lane >> 4) * 4;
    f32x4 acc[CJ];
#pragma unroll
    for (int j = 0; j < CJ; ++j) acc[j] = (f32x4){0.f, 0.f, 0.f, 0.f};

#pragma unroll
    for (int kk = 0; kk < KS; ++kk) {
        bf16x8 a = *(const bf16x8*)&sX[(r0 + l15) * KP2 + koff + kk * 16];
        bf16x8 b[CJ];
#pragma unroll
        for (int j = 0; j < CJ; ++j)
            b[j] = *(const bf16x8*)&sW[(j * 16 + l15) * KP2 + koff + kk * 16];
#pragma unroll
        for (int j = 0; j < CJ; ++j)
            acc[j] = __builtin_amdgcn_mfma_f32_16x16x32_bf16(a, b[j], acc[j], 0, 0, 0);
    }

    const int orow0 = r0 + ((lane >> 4) << 2);
#pragma unroll
    for (int j = 0; j < CJ; ++j) {
        const int c = j * 16 + l15;
#pragma unroll
        for (int q = 0; q < 4; ++q) {
            float v = acc[j][q];
            const int row = orow0 + q;
            if (BLEND) {
                unsigned u = sX[row * KP2 + (c >> 1)];
                float hv = __uint_as_float((c & 1) ? (u & 0xffff0000u) : (u << 16));
                v = (1.0f - beta) * hv + beta * v;
            }
            float p = __shfl_xor(v, 1);
            const int n = nbase + row;
            if (!(lane & 1) && n < N_NODES && c < C)
                outb[(size_t)n * (C / 2) + (c >> 1)] = packbf(v, p);
        }
        if (STATS) {
            float s = acc[j][0] + acc[j][1] + acc[j][2] + acc[j][3];
            float q2 = acc[j][0] * acc[j][0] + acc[j][1] * acc[j][1] +
                       acc[j][2] * acc[j][2] + acc[j][3] * acc[j][3];
            s  += __shfl_xor(s, 16);  s  += __shfl_xor(s, 32);
            q2 += __shfl_xor(q2, 16); q2 += __shfl_xor(q2, 32);
            if (lane < 16) {
                sstat[(j * 16 + lane) * 4 + wid] = s;
                sstatq[(j * 16 + lane) * 4 + wid] = q2;
            }
        }
    }

    if (H0OUT) {
        for (int i = tid; i < 64 * (C / 2); i += 256) {
            int r = i / (C / 2), c2 = i - r * (C / 2);
            int n = nbase + r;
            if (n < N_NODES) h0n[(size_t)n * (C / 2) + c2] = sX[r * KP2 + c2];
        }
    }

    if (STATS) {
        __syncthreads();
        if (tid < C) {
            float s = sstat[tid * 4] + sstat[tid * 4 + 1] + sstat[tid * 4 + 2] +
                      sstat[tid * 4 + 3];
            float q = sstatq[tid * 4] + sstatq[tid * 4 + 1] + sstatq[tid * 4 + 2] +
                      sstatq[tid * 4 + 3];
            const int rep = ((int)blockIdx.x & (NREP - 1)) * 2 * HID_CH;
            atomicAdd(&stat[rep + tid], s);
            atomicAdd(&stat[rep + HID_CH + tid], q);
        }
    }
}

// ---------------- SpMM v5b: bf16 gather table; stats into replicated slots ----------------

template <int C, bool LAYER, bool STATS, bool PACKO>
__global__ __launch_bounds__(256) void spmm5(
    const uint4* __restrict__ tb, const uint4* __restrict__ h0n,
    const int* __restrict__ row_start, const int2* __restrict__ cw,
    const float* __restrict__ selfw, float* __restrict__ outf, uint4* __restrict__ outp,
    float* __restrict__ stat) {
    constexpr int C8 = C / 8;
    __shared__ float ssum[STATS ? C : 1];
    __shared__ float ssq[STATS ? C : 1];
    const int tid = threadIdx.x;
    if (STATS) {
        if (tid < C) { ssum[tid] = 0.0f; ssq[tid] = 0.0f; }
        __syncthreads();
    }
    const int total = N_NODES * C8;
    for (int idx = blockIdx.x * 256 + tid; idx < total; idx += gridDim.x * 256) {
        const int n = idx / C8;
        const int c8 = idx - n * C8;
        const float sw = selfw[n];
        f8 acc = unpack8(tb[idx]);
        acc.lo.x *= sw; acc.lo.y *= sw; acc.lo.z *= sw; acc.lo.w *= sw;
        acc.hi.x *= sw; acc.hi.y *= sw; acc.hi.z *= sw; acc.hi.w *= sw;
        const int rs = row_start[n], re = row_start[n + 1];
        int j = rs;
        for (; j + 3 < re; j += 4) {
            int2 e0 = cw[j], e1 = cw[j + 1], e2 = cw[j + 2], e3 = cw[j + 3];
            uint4 p0 = tb[(size_t)e0.x * C8 + c8];
            uint4 p1 = tb[(size_t)e1.x * C8 + c8];
            uint4 p2 = tb[(size_t)e2.x * C8 + c8];
            uint4 p3 = tb[(size_t)e3.x * C8 + c8];
            float w0 = __int_as_float(e0.y), w1 = __int_as_float(e1.y);
            float w2 = __int_as_float(e2.y), w3 = __int_as_float(e3.y);
            f8 a0 = unpack8(p0), a1 = unpack8(p1), a2 = unpack8(p2), a3 = unpack8(p3);
            acc.lo.x = fmaf(w0, a0.lo.x, acc.lo.x); acc.lo.y = fmaf(w0, a0.lo.y, acc.lo.y);
            acc.lo.z = fmaf(w0, a0.lo.z, acc.lo.z); acc.lo.w = fmaf(w0, a0.lo.w, acc.lo.w);
            acc.hi.x = fmaf(w0, a0.hi.x, acc.hi.x); acc.hi.y = fmaf(w0, a0.hi.y, acc.hi.y);
            acc.hi.z = fmaf(w0, a0.hi.z, acc.hi.z); acc.hi.w = fmaf(w0, a0.hi.w, acc.hi.w);
            acc.lo.x = fmaf(w1, a1.lo.x, acc.lo.x); acc.lo.y = fmaf(w1, a1.lo.y, acc.lo.y);
            acc.lo.z = fmaf(w1, a1.lo.z, acc.lo.z); acc.lo.w = fmaf(w1, a1.lo.w, acc.lo.w);
            acc.hi.x = fmaf(w1, a1.hi.x, acc.hi.x); acc.hi.y = fmaf(w1, a1.hi.y, acc.hi.y);
            acc.hi.z = fmaf(w1, a1.hi.z, acc.hi.z); acc.hi.w = fmaf(w1, a1.hi.w, acc.hi.w);
            acc.lo.x = fmaf(w2, a2.lo.x, acc.lo.x); acc.lo.y = fmaf(w2, a2.lo.y, acc.lo.y);
            acc.lo.z = fmaf(w2, a2.lo.z, acc.lo.z); acc.lo.w = fmaf(w2, a2.lo.w, acc.lo.w);
            acc.hi.x = fmaf(w2, a2.hi.x, acc.hi.x); acc.hi.y = fmaf(w2, a2.hi.y, acc.hi.y);
            acc.hi.z = fmaf(w2, a2.hi.z, acc.hi.z); acc.hi.w = fmaf(w2, a2.hi.w, acc.hi.w);
            acc.lo.x = fmaf(w3, a3.lo.x, acc.lo.x); acc.lo.y = fmaf(w3, a3.lo.y, acc.lo.y);
            acc.lo.z = fmaf(w3, a3.lo.z, acc.lo.z); acc.lo.w = fmaf(w3, a3.lo.w, acc.lo.w);
            acc.hi.x = fmaf(w3, a3.hi.x, acc.hi.x); acc.hi.y = fmaf(w3, a3.hi.y, acc.hi.y);
            acc.hi.z = fmaf(w3, a3.hi.z, acc.hi.z); acc.hi.w = fmaf(w3, a3.hi.w, acc.hi.w);
        }
        for (; j < re; ++j) {
            int2 e0 = cw[j];
            uint4 p0 = tb[(size_t)e0.x * C8 + c8];
            float w0 = __int_as_float(e0.y);
            f8 a0 = unpack8(p0);
            acc.lo.x = fmaf(w0, a0.lo.x, acc.lo.x); acc.lo.y = fmaf(w0, a0.lo.y, acc.lo.y);
            acc.lo.z = fmaf(w0, a0.lo.z, acc.lo.z); acc.lo.w = fmaf(w0, a0.lo.w, acc.lo.w);
            acc.hi.x = fmaf(w0, a0.hi.x, acc.hi.x); acc.hi.y = fmaf(w0, a0.hi.y, acc.hi.y);
            acc.hi.z = fmaf(w0, a0.hi.z, acc.hi.z); acc.hi.w = fmaf(w0, a0.hi.w, acc.hi.w);
        }
        if (LAYER) {
            f8 h0 = unpack8(h0n[idx]);
            acc.lo.x = 0.9f * acc.lo.x + 0.1f * h0.lo.x;
            acc.lo.y = 0.9f * acc.lo.y + 0.1f * h0.lo.y;
            acc.lo.z = 0.9f * acc.lo.z + 0.1f * h0.lo.z;
            acc.lo.w = 0.9f * acc.lo.w + 0.1f * h0.lo.w;
            acc.hi.x = 0.9f * acc.hi.x + 0.1f * h0.hi.x;
            acc.hi.y = 0.9f * acc.hi.y + 0.1f * h0.hi.y;
            acc.hi.z = 0.9f * acc.hi.z + 0.1f * h0.hi.z;
            acc.hi.w = 0.9f * acc.hi.w + 0.1f * h0.hi.w;
        }
        if (PACKO) {
            uint4 pk;
            pk.x = packbf(acc.lo.x, acc.lo.y); pk.y = packbf(acc.lo.z, acc.lo.w);
            pk.z = packbf(acc.hi.x, acc.hi.y); pk.w = packbf(acc.hi.z, acc.hi.w);
            outp[idx] = pk;
        } else {
            float* op = outf + (size_t)n * C + c8 * 8;
            *(float4*)op = acc.lo;
            *(float4*)(op + 4) = acc.hi;
        }
        if (STATS) {
            int c = c8 * 8;
            atomicAdd(&ssum[c + 0], acc.lo.x); atomicAdd(&ssq[c + 0], acc.lo.x * acc.lo.x);
            atomicAdd(&ssum[c + 1], acc.lo.y); atomicAdd(&ssq[c + 1], acc.lo.y * acc.lo.y);
            atomicAdd(&ssum[c + 2], acc.lo.z); atomicAdd(&ssq[c + 2], acc.lo.z * acc.lo.z);
            atomicAdd(&ssum[c + 3], acc.lo.w); atomicAdd(&ssq[c + 3], acc.lo.w * acc.lo.w);
            atomicAdd(&ssum[c + 4], acc.hi.x); atomicAdd(&ssq[c + 4], acc.hi.x * acc.hi.x);
            atomicAdd(&ssum[c + 5], acc.hi.y); atomicAdd(&ssq[c + 5], acc.hi.y * acc.hi.y);
            atomicAdd(&ssum[c + 6], acc.hi.z); atomicAdd(&ssq[c + 6], acc.hi.z * acc.hi.z);
            atomicAdd(&ssum[c + 7], acc.hi.w); atomicAdd(&ssq[c + 7], acc.hi.w * acc.hi.w);
        }
    }
    if (STATS) {
        __syncthreads();
        if (tid < C) {
            const int rep = ((int)blockIdx.x & (NREP - 1)) * 2 * HID_CH;
            atomicAdd(&stat[rep + tid], ssum[tid]);
            atomicAdd(&stat[rep + HID_CH + tid], ssq[tid]);
        }
    }
}

// ---------------- launch ----------------

extern "C" void kernel_launch(void* const* d_in, const int* in_sizes, int n_in,
                              void* d_out, int out_size, void* d_ws, size_t ws_size,
                              hipStream_t stream) {
    const float* x  = (const float*)d_in[0];
    const int*   ei = (const int*)d_in[1];
    const float* W0 = (const float*)d_in[2];
    const float* W1 = (const float*)d_in[3];
    const float* W2 = (const float*)d_in[4];
    const float* W3 = (const float*)d_in[5];
    float* out = (float*)d_out;

    char* w = (char*)d_ws;
    auto alloc = [&](size_t bytes) {
        void* p = (void*)w;
        w += (bytes + 255) & ~(size_t)255;
        return p;
    };
    const int STATB = NREP * 2 * HID_CH;
    int*      cnt       = (int*)alloc(N_NODES * 4);
    int*      row_start = (int*)alloc((N_NODES + 1) * 4);
    int*      fillp     = (int*)alloc(N_NODES * 4);
    int*      bsum      = (int*)alloc(NBK * 4);
    int*      bexc      = (int*)alloc(NBK * 4);
    int2*     cw        = (int2*)alloc((size_t)N_EDGES * 8);
    float*    dinv      = (float*)alloc(N_NODES * 4);
    float*    selfw     = (float*)alloc(N_NODES * 4);
    unsigned* g0b       = (unsigned*)alloc((size_t)N_NODES * (HID_CH / 2) * 4);
    unsigned* sb        = (unsigned*)alloc((size_t)N_NODES * (HID_CH / 2) * 4);
    unsigned* tb        = (unsigned*)alloc((size_t)N_NODES * (HID_CH / 2) * 4);
    unsigned* h0n       = (unsigned*)alloc((size_t)N_NODES * (HID_CH / 2) * 4);
    float*    stat0     = (float*)alloc(STATB * 4);
    float*    stat1     = (float*)alloc(STATB * 4);
    float*    stat2     = (float*)alloc(STATB * 4);
    float*    mu0  = (float*)alloc(HID_CH * 4);
    float*    inv0 = (float*)alloc(HID_CH * 4);
    float*    mu1  = (float*)alloc(HID_CH * 4);
    float*    inv1 = (float*)alloc(HID_CH * 4);
    float*    mu2  = (float*)alloc(HID_CH * 4);
    float*    inv2 = (float*)alloc(HID_CH * 4);

    const int EB = (N_EDGES + 255) / 256;
    const int G64 = (N_NODES + 63) / 64;

    hipMemsetAsync(cnt, 0, N_NODES * 4, stream);
    hipMemsetAsync(stat0, 0, (size_t)STATB * 3 * 4 + 512, stream);

    count_kernel<<<EB, 256, 0, stream>>>(ei, cnt);
    scan_a<<<NBK, 256, 0, stream>>>(cnt, bsum);
    scan_b<<<1, 256, 0, stream>>>(bsum, bexc, row_start);
    scan_c<<<NBK, 256, 0, stream>>>(cnt, bexc, row_start, dinv, selfw, fillp);
    fill_kernel<<<EB, 256, 0, stream>>>(ei, row_start, fillp, dinv, cw);

    // layer 0: g0b = bf16(x @ W0^T) + stats0
    gemm7<IN_CH, HID_CH, 96, false, false, false, true, false>
        <<<G64, 256, 0, stream>>>(x, W0, g0b, nullptr, nullptr, nullptr, stat0, 0.0f);
    bn_fin<<<1, HID_CH, 0, stream>>>(stat0, mu0, inv0);

    // layer 1: tb = bf16(blend(hn0, hn0@W1^T, .5)); h0n = bf16(hn0)
    gemm7<HID_CH, HID_CH, 96, true, true, true, false, true>
        <<<G64, 256, 0, stream>>>(g0b, W1, tb, h0n, mu0, inv0, nullptr, 0.5f);
    spmm5<HID_CH, true, true, true><<<2344, 256, 0, stream>>>(
        (const uint4*)tb, (const uint4*)h0n, row_start, cw, selfw, nullptr, (uint4*)sb, stat1);
    bn_fin<<<1, HID_CH, 0, stream>>>(stat1, mu1, inv1);

    // layer 2: tb = bf16(blend(hn1, hn1@W2^T, .25))
    gemm7<HID_CH, HID_CH, 96, true, true, true, false, false>
        <<<G64, 256, 0, stream>>>(sb, W2, tb, nullptr, mu1, inv1, nullptr, 0.25f);
    spmm5<HID_CH, true, true, true><<<2344, 256, 0, stream>>>(
        (const uint4*)tb, (const uint4*)h0n, row_start, cw, selfw, nullptr, (uint4*)sb, stat2);
    bn_fin<<<1, HID_CH, 0, stream>>>(stat2, mu2, inv2);

    // final: tb = bf16(hn2 @ W3^T); out = spmm(tb)
    gemm7<HID_CH, OUT_CH, 48, true, false, true, false, false>
        <<<G64, 256, 0, stream>>>(sb, W3, tb, nullptr, mu2, inv2, nullptr, 0.0f);
    spmm5<OUT_CH, false, false, false><<<977, 256, 0, stream>>>(
        (const uint4*)tb, nullptr, row_start, cw, selfw, out, nullptr, nullptr);
}